// Round 13
// baseline (3744.675 us; speedup 1.0000x reference)
//
#include <hip/hip_runtime.h>
#include <cstdint>
#include <cstddef>

#define NB 256   // batch
#define NT 512   // time steps
#define ND 64    // input dim
#define NH 512   // hidden dim

typedef __attribute__((ext_vector_type(8))) _Float16 half8;
typedef __attribute__((ext_vector_type(4))) float f32x4;
typedef unsigned long long ull;

union H8 { half8 h; ull q[2]; };

__device__ __forceinline__ float tanh_fast(float x) {
  float ax = fabsf(x);
  float e  = __expf(-2.0f * ax);
  float t  = (1.0f - e) * __frcp_rn(1.0f + e);
  return copysignf(t, x);
}

// Pack W (W_hh | W_ih) to fp16 fragment-major (same as R10):
//   unit u = ((kt*4 + cb)*8 + j)*64 + lane, 8 halves each;
//   n = cb*128 + j*16 + (lane&15); k = kt*32 + (lane>>4)*8 + e.
__global__ void prep_kernel(const float* __restrict__ whh,
                            const float* __restrict__ wih,
                            _Float16* __restrict__ wpk) {
  const int id = blockIdx.x * 256 + threadIdx.x;   // 0..36863
  if (id >= 18 * 4 * 8 * 64) return;
  const int lane = id & 63;
  const int j    = (id >> 6) & 7;
  const int cbv  = (id >> 9) & 3;
  const int kt   = id >> 11;
  const int n    = cbv * 128 + j * 16 + (lane & 15);
  const int kb   = kt * 32 + (lane >> 4) * 8;
  half8 o;
#pragma unroll
  for (int e = 0; e < 8; ++e) {
    const int k = kb + e;
    const float v = (kt < 16) ? whh[(size_t)n * NH + k]
                              : wih[(size_t)n * ND + (k - NH)];
    o[e] = (_Float16)v;
  }
  *(half8*)(wpk + (size_t)id * 8) = o;
}

// Zero flags every call (d_ws not re-poisoned between replays).
__global__ void init_kernel(unsigned int* __restrict__ flags) {
  int i = blockIdx.x * 256 + threadIdx.x;
  if (i < 4096) flags[i] = 0u;
}

__global__ void combine_kernel(const float* __restrict__ partial,
                               const float* __restrict__ bho,
                               float* __restrict__ out) {
  int id = blockIdx.x * 256 + threadIdx.x;   // 131072
  out[id] = bho[0] + partial[id] + partial[id + NB * NT]
          + partial[id + 2 * NB * NT] + partial[id + 3 * NB * NT];
}

// Two-stream column-split persistent RNN (fp16):
// 32 blocks = 8 super-groups x 4 cb; block = 2 batch-groups x 16 rows x 128 cols.
// W fully stationary in VGPRs. h in LDS per stream. Streams alternate so
// stream A's publish/flag/fetch latency hides under stream B's compute.
// R13 fix vs R12: hglob plane stride 64 -> 128 ull (16x32 halves = 128 ull;
// R12's 64 made hi/lo planes and adjacent gk regions overlap -> corruption).
__global__ __launch_bounds__(256, 1) void rnn_2s(
    const float* __restrict__ x, const _Float16* __restrict__ wpk,
    const float* __restrict__ bih, const float* __restrict__ bhh,
    const float* __restrict__ who,
    ull* __restrict__ hglob,          // [2 tbuf][16 bg][16 gk][2 p][128] ull
    unsigned int* __restrict__ flags, // [(bg*4+cb)*4 + w] * 16 u32
    float* __restrict__ partial)      // [4 cb][NB][NT] f32
{
  __shared__ _Float16 hpeer[2][2][16][536];   // 134 KiB: [stream][plane][row][col]
  __shared__ _Float16 tstage[4][2][16][40];   // 10 KiB
  __shared__ float posum[2][4][16];

  const int bid  = blockIdx.x;
  const int sg   = bid >> 2;
  const int cb   = bid & 3;
  const int bg0  = sg * 2, bg1 = sg * 2 + 1;
  const int w    = threadIdx.x >> 6;
  const int lane = threadIdx.x & 63;
  const int lm   = lane & 15;
  const int lg   = lane >> 4;
  const int lkb  = lg * 8;
  const int bm0  = bg0 * 16, bm1 = bg1 * 16;
  const int n0   = cb * 128 + w * 32;
  const int gk   = cb * 4 + w;

  // ---- W fully in VGPRs: wv[18 kt][2 nt] ----
  half8 wv[18][2];
#pragma unroll
  for (int kt = 0; kt < 18; ++kt)
#pragma unroll
    for (int nt = 0; nt < 2; ++nt)
      wv[kt][nt] = *(const half8*)(wpk +
        (size_t)(((kt * 4 + cb) * 8 + (w * 2 + nt)) * 64 + lane) * 8);

  float bv[2], wov[2];
#pragma unroll
  for (int nt = 0; nt < 2; ++nt) {
    const int n = n0 + nt * 16 + lm;
    bv[nt]  = bih[n] + bhh[n];
    wov[nt] = who[n];
  }

  const float* xrow0 = x + (size_t)(bm0 + lm) * NT * ND + lkb;
  const float* xrow1 = x + (size_t)(bm1 + lm) * NT * ND + lkb;
  f32x4 xr0[4], xr1[4];
#pragma unroll
  for (int xt = 0; xt < 2; ++xt) {
    xr0[2 * xt]     = *(const f32x4*)(xrow0 + xt * 32);
    xr0[2 * xt + 1] = *(const f32x4*)(xrow0 + xt * 32 + 4);
    xr1[2 * xt]     = *(const f32x4*)(xrow1 + xt * 32);
    xr1[2 * xt + 1] = *(const f32x4*)(xrow1 + xt * 32 + 4);
  }

  // fetch decode tables: 3 peers x 4 gk x 2 p x 128 ull = 3072 ull / 256 = 12
  int goff[12], boff[12];
#pragma unroll
  for (int k = 0; k < 12; ++k) {
    const int idx = threadIdx.x + k * 256;
    const int pc  = idx >> 7, off = idx & 127;
    const int pi  = pc >> 3, rem = pc & 7;
    const int gkw = rem >> 1, p = rem & 1;
    const int scb = pi + (pi >= cb);
    goff[k] = ((scb * 4 + gkw) * 2 + p) * 128 + off;   // 128-ull plane stride
    boff[k] = (((p * 16) + (off >> 3)) * 536 + scb * 128 + gkw * 32 + (off & 7) * 4) * 2;
  }

  unsigned int* myf0 = flags + ((bg0 * 4 + cb) * 4 + w) * 16;
  unsigned int* myf1 = flags + ((bg1 * 4 + cb) * 4 + w) * 16;
  const int spi  = lane >> 2;
  const int sscb = (lane < 12) ? spi + (spi >= cb) : 0;
  const unsigned int* sf0 = flags + ((bg0 * 4 + sscb) * 4 + (lane & 3)) * 16;
  const unsigned int* sf1 = flags + ((bg1 * 4 + sscb) * 4 + (lane & 3)) * 16;

  ull fq[12];

#define SPIN(SF, TGT) do {                                                    \
    const unsigned _tg = (unsigned)(TGT);                                     \
    for (;;) {                                                                \
      unsigned _vv = _tg;                                                     \
      if (lane < 12)                                                          \
        _vv = __hip_atomic_load((SF), __ATOMIC_RELAXED, __HIP_MEMORY_SCOPE_AGENT); \
      if (__all(_vv >= _tg)) break;                                           \
      __builtin_amdgcn_s_sleep(1);                                            \
    }                                                                         \
    asm volatile("" ::: "memory");                                            \
  } while (0)

#define FETCH(TB, BGI) do {                                                   \
    const ull* _gb = hglob + ((size_t)(TB) * 16 + (BGI)) * (16 * 2 * 128);    \
    _Pragma("unroll")                                                         \
    for (int _k = 0; _k < 12; ++_k)                                           \
      fq[_k] = __hip_atomic_load(_gb + goff[_k], __ATOMIC_RELAXED,            \
                                 __HIP_MEMORY_SCOPE_AGENT);                   \
    asm volatile("" ::: "memory");                                            \
  } while (0)

#define STAGE(S) do {                                                         \
    char* _hb = (char*)&hpeer[S][0][0][0];                                    \
    _Pragma("unroll")                                                         \
    for (int _k = 0; _k < 12; ++_k) *(ull*)(_hb + boff[_k]) = fq[_k];         \
  } while (0)

#define PUBLISH(T, BGI) do {                                                  \
    const int _pr = lane >> 2, _pq = lane & 3;                                \
    ull* _pb = hglob + ((((size_t)((T) & 1) * 16 + (BGI)) * 16 + gk) * 2) * 128; \
    _Pragma("unroll")                                                         \
    for (int _p = 0; _p < 2; ++_p) {                                          \
      H8 _u; _u.h = *(const half8*)&tstage[w][_p][_pr][_pq * 8];              \
      ull* _d = _pb + _p * 128 + _pr * 8 + _pq * 2;                           \
      __hip_atomic_store(_d,     _u.q[0], __ATOMIC_RELAXED, __HIP_MEMORY_SCOPE_AGENT); \
      __hip_atomic_store(_d + 1, _u.q[1], __ATOMIC_RELAXED, __HIP_MEMORY_SCOPE_AGENT); \
    }                                                                         \
  } while (0)

  // compute + barrier + epilogue (WH=0: h(-1)=0 prologue variant)
#define STEPBODY(S, T, XR, XROW, WH) do {                                     \
    half8 _axh[2], _axl[2];                                                   \
    _Pragma("unroll")                                                         \
    for (int _xt = 0; _xt < 2; ++_xt) {                                       \
      float _v[8];                                                            \
      *(f32x4*)&_v[0] = XR[2 * _xt]; *(f32x4*)&_v[4] = XR[2 * _xt + 1];       \
      _Pragma("unroll")                                                       \
      for (int _e = 0; _e < 8; ++_e) {                                        \
        _Float16 _hi = (_Float16)_v[_e];                                      \
        _axh[_xt][_e] = _hi;                                                  \
        _axl[_xt][_e] = (_Float16)(_v[_e] - (float)_hi);                      \
      }                                                                       \
    }                                                                         \
    f32x4 _acc[2][2];                                                         \
    _acc[0][0] = (f32x4){0.f,0.f,0.f,0.f}; _acc[0][1] = (f32x4){0.f,0.f,0.f,0.f}; \
    _acc[1][0] = (f32x4){0.f,0.f,0.f,0.f}; _acc[1][1] = (f32x4){0.f,0.f,0.f,0.f}; \
    if (WH) {                                                                 \
      _Pragma("unroll")                                                       \
      for (int _kt = 0; _kt < 16; ++_kt) {                                    \
        half8 _ah = *(const half8*)&hpeer[S][0][lm][_kt * 32 + lkb];          \
        half8 _al = *(const half8*)&hpeer[S][1][lm][_kt * 32 + lkb];          \
        _Pragma("unroll")                                                     \
        for (int _nt = 0; _nt < 2; ++_nt) {                                   \
          _acc[_nt][0] = __builtin_amdgcn_mfma_f32_16x16x32_f16(_ah, wv[_kt][_nt], _acc[_nt][0], 0, 0, 0); \
          _acc[_nt][1] = __builtin_amdgcn_mfma_f32_16x16x32_f16(_al, wv[_kt][_nt], _acc[_nt][1], 0, 0, 0); \
        }                                                                     \
      }                                                                       \
    }                                                                         \
    _Pragma("unroll")                                                         \
    for (int _q = 0; _q < 2; ++_q)                                            \
      _Pragma("unroll")                                                       \
      for (int _nt = 0; _nt < 2; ++_nt) {                                     \
        _acc[_nt][0] = __builtin_amdgcn_mfma_f32_16x16x32_f16(_axh[_q], wv[16 + _q][_nt], _acc[_nt][0], 0, 0, 0); \
        _acc[_nt][1] = __builtin_amdgcn_mfma_f32_16x16x32_f16(_axl[_q], wv[16 + _q][_nt], _acc[_nt][1], 0, 0, 0); \
      }                                                                       \
    if ((T) + 1 < NT) {                                                       \
      _Pragma("unroll")                                                       \
      for (int _xt = 0; _xt < 2; ++_xt) {                                     \
        XR[2 * _xt]     = *(const f32x4*)((XROW) + (size_t)((T) + 1) * ND + _xt * 32);     \
        XR[2 * _xt + 1] = *(const f32x4*)((XROW) + (size_t)((T) + 1) * ND + _xt * 32 + 4); \
      }                                                                       \
    }                                                                         \
    __syncthreads(); /* all waves done reading hpeer[S] before own-stage */   \
    float _po[4] = {0.f, 0.f, 0.f, 0.f};                                      \
    _Pragma("unroll")                                                         \
    for (int _nt = 0; _nt < 2; ++_nt) {                                       \
      _Pragma("unroll")                                                       \
      for (int _r = 0; _r < 4; ++_r) {                                        \
        float _pre = _acc[_nt][0][_r] + _acc[_nt][1][_r] + bv[_nt];           \
        float _hv  = tanh_fast(_pre);                                         \
        const int _m = lg * 4 + _r;                                           \
        _Float16 _hi = (_Float16)_hv;                                         \
        _Float16 _lo = (_Float16)(_hv - (float)_hi);                          \
        tstage[w][0][_m][_nt * 16 + lm] = _hi;                                \
        tstage[w][1][_m][_nt * 16 + lm] = _lo;                                \
        hpeer[S][0][_m][n0 + _nt * 16 + lm] = _hi;                            \
        hpeer[S][1][_m][n0 + _nt * 16 + lm] = _lo;                            \
        _po[_r] += _hv * wov[_nt];                                            \
      }                                                                       \
    }                                                                         \
    _Pragma("unroll")                                                         \
    for (int _s = 1; _s < 16; _s <<= 1)                                       \
      _Pragma("unroll")                                                       \
      for (int _r = 0; _r < 4; ++_r) _po[_r] += __shfl_xor(_po[_r], _s, 64);  \
    if (lm == 0) {                                                            \
      _Pragma("unroll")                                                       \
      for (int _r = 0; _r < 4; ++_r) posum[S][w][lg * 4 + _r] = _po[_r];      \
    }                                                                         \
  } while (0)

  // ---------------- prologue: t = 0, h(-1) = 0 ----------------
  STEPBODY(0, 0, xr0, xrow0, 0);
  PUBLISH(0, bg0);
  asm volatile("s_waitcnt vmcnt(0)" ::: "memory");
  if (lane == 0)
    __hip_atomic_store(myf0, 1u, __ATOMIC_RELAXED, __HIP_MEMORY_SCOPE_AGENT);

  STEPBODY(1, 0, xr1, xrow1, 0);
  PUBLISH(0, bg1);
  asm volatile("s_waitcnt vmcnt(0)" ::: "memory");
  if (lane == 0)
    __hip_atomic_store(myf1, 1u, __ATOMIC_RELAXED, __HIP_MEMORY_SCOPE_AGENT);

  __syncthreads();
  if (w == 0 && lane < 16) {
    float a = posum[0][0][lane] + posum[0][1][lane] + posum[0][2][lane] + posum[0][3][lane];
    float b = posum[1][0][lane] + posum[1][1][lane] + posum[1][2][lane] + posum[1][3][lane];
    partial[((size_t)cb * NB + bm0 + lane) * NT + 0] = a;
    partial[((size_t)cb * NB + bm1 + lane) * NT + 0] = b;
  }
  SPIN(sf0, 1);
  FETCH(0, bg0);   // h_s0(0), staged at ustep(0,1)

  // ---------------- main loop ----------------
  for (int t = 1; t < NT; ++t) {
    // ======== ustep (stream 0, t) ========
    asm volatile("s_waitcnt vmcnt(0)" ::: "memory");   // fetch + s1 stores done
    if (lane == 0)
      __hip_atomic_store(myf1, (unsigned)t, __ATOMIC_RELAXED, __HIP_MEMORY_SCOPE_AGENT);
    STAGE(0);
    __syncthreads();
    if (w == 0 && lane < 16) {   // partial for (s1, t-1)
      float s4 = posum[1][0][lane] + posum[1][1][lane] + posum[1][2][lane] + posum[1][3][lane];
      partial[((size_t)cb * NB + bm1 + lane) * NT + (t - 1)] = s4;
    }
    SPIN(sf1, t);
    FETCH((t - 1) & 1, bg1);     // h_s1(t-1); RTT hides under compute s0(t)
    STEPBODY(0, t, xr0, xrow0, 1);
    PUBLISH(t, bg0);

    // ======== ustep (stream 1, t) ========
    asm volatile("s_waitcnt vmcnt(0)" ::: "memory");
    if (lane == 0)
      __hip_atomic_store(myf0, (unsigned)(t + 1), __ATOMIC_RELAXED, __HIP_MEMORY_SCOPE_AGENT);
    STAGE(1);
    __syncthreads();
    if (w == 0 && lane < 16) {   // partial for (s0, t)
      float s4 = posum[0][0][lane] + posum[0][1][lane] + posum[0][2][lane] + posum[0][3][lane];
      partial[((size_t)cb * NB + bm0 + lane) * NT + t] = s4;
    }
    if (t + 1 < NT) {
      SPIN(sf0, t + 1);
      FETCH(t & 1, bg0);         // h_s0(t); RTT hides under compute s1(t)
    }
    STEPBODY(1, t, xr1, xrow1, 1);
    PUBLISH(t, bg1);
  }

  // tail: partial for (s1, 511)
  asm volatile("s_waitcnt vmcnt(0)" ::: "memory");
  __syncthreads();
  if (w == 0 && lane < 16) {
    float s4 = posum[1][0][lane] + posum[1][1][lane] + posum[1][2][lane] + posum[1][3][lane];
    partial[((size_t)cb * NB + bm1 + lane) * NT + (NT - 1)] = s4;
  }

#undef SPIN
#undef FETCH
#undef STAGE
#undef PUBLISH
#undef STEPBODY
}

extern "C" void kernel_launch(void* const* d_in, const int* in_sizes, int n_in,
                              void* d_out, int out_size, void* d_ws, size_t ws_size,
                              hipStream_t stream) {
  const float* x   = (const float*)d_in[0];
  const float* wih = (const float*)d_in[1];
  const float* whh = (const float*)d_in[2];
  const float* bih = (const float*)d_in[3];
  const float* bhh = (const float*)d_in[4];
  const float* who = (const float*)d_in[5];
  const float* bho = (const float*)d_in[6];
  float* out = (float*)d_out;

  // ws: wpk 576KB | hglob 1MB | flags 16KB | partial 2MB
  _Float16* wpk = (_Float16*)d_ws;
  ull* hglob = (ull*)(wpk + (size_t)18 * 4 * 8 * 64 * 8);
  unsigned int* flags = (unsigned int*)(hglob + (size_t)2 * 16 * 16 * 2 * 128);
  float* partial = (float*)(flags + 4096);

  init_kernel<<<16, 256, 0, stream>>>(flags);
  prep_kernel<<<144, 256, 0, stream>>>(whh, wih, wpk);
  rnn_2s<<<32, 256, 0, stream>>>(x, wpk, bih, bhh, who, hglob, flags, partial);
  combine_kernel<<<512, 256, 0, stream>>>(partial, bho, out);
}